// Round 12
// baseline (93.657 us; speedup 1.0000x reference)
//
#include <hip/hip_runtime.h>
#include <hip/hip_bf16.h>

#define BB 256      // drug pairs
#define NP 40       // atoms per graph
#define HH 128      // hidden dim
#define EST2 68     // E row stride (floats) for the 64-col half (+4 pad)
#define NT 512      // threads per block; 512 blocks = 2 blocks/CU
#define AROWB 272   // bf16-A LDS row stride bytes (256 + 16 pad)
#define NROWS 80    // A1 rows 0-39, A2 rows 40-79
#define NBLK (2*BB)

typedef __attribute__((ext_vector_type(8))) short bf16x8;
typedef __attribute__((ext_vector_type(4))) float f32x4;
typedef __attribute__((ext_vector_type(2))) float f32x2;

static __device__ __forceinline__ short bfs(float f) {
    union { __hip_bfloat16 h; short s; } u;
    u.h = __float2bfloat16(f);          // RTNE
    return u.s;
}

// packed 2-elem tanh-sum step (R10): acc2 += (wswap*D) * rcp(D.x*D.y)
#define PB2(acc2, e1p, e2p, wsp) do {                              \
    f32x2 D_  = __builtin_elementwise_fma((e1p), (e2p), one2);     \
    float r_  = __builtin_amdgcn_rcpf(D_.x * D_.y);                \
    f32x2 rs_ = {r_, r_};                                          \
    acc2 = __builtin_elementwise_fma((wsp) * D_, rs_, acc2);       \
} while (0)

__global__ __launch_bounds__(NT, 4) void ddi_half(
    const float* __restrict__ h1, const float* __restrict__ h2,
    const float* __restrict__ W1, const float* __restrict__ b1,
    const float* __restrict__ W2, const float* __restrict__ b2,
    float* __restrict__ ws, unsigned* __restrict__ cnt,
    float* __restrict__ out)
{
    const int bid = blockIdx.x;
    const int b   = bid >> 1;        // pair
    const int hf  = bid & 1;         // h-half: cols [64*hf, 64*hf+64)
    const int t = threadIdx.x;
    const int l = t & 63;
    const int w = t >> 6;            // 8 waves
    const int l4 = l >> 4;
    const int lr = l & 15;

    __shared__ __align__(16) char  sAB[NROWS*AROWB];   // 21760 B bf16 A1|A2
    __shared__ __align__(16) float sE[2*NP*EST2];      // 21760 B E1|E2 (64-col half)
    __shared__ __align__(16) float sPar[1600];         // partials, then pu
    __shared__ __align__(16) float sW2S[64];           // w2 half, pair-swapped
    __shared__ float sRed[8];
    __shared__ float sCL;
    __shared__ unsigned sTicket;

    const float L2E = 1.44269504088896340736f;
    const float K   = 2.88539008177792681472f;   // 2*log2(e)

    // ---- W1 fragments for this h-half (A-operand = W^T) ----
    const int m   = w >> 2;          // matrix 0/1
    const int hml = w & 3;           // local h-tile 0..3
    const int hbl = hml*16 + l4*4;   // local E col base
    const float* Wb = W1 + (size_t)m*HH*HH + hf*64 + hml*16 + lr;
    float wraw[4][8];
    #pragma unroll
    for (int ks = 0; ks < 4; ++ks)
        #pragma unroll
        for (int j = 0; j < 8; ++j)
            wraw[ks][j] = Wb[(size_t)(ks*32 + (l4<<3) + j) * HH];
    float4 kbK = make_float4(0.f,0.f,0.f,0.f);
    if (m == 0) {
        float4 bv = *(const float4*)(b1 + hf*64 + hbl);
        kbK = make_float4(K*bv.x, K*bv.y, K*bv.z, K*bv.w);
    }

    // ---- stage A as bf16 (80 rows x full 128 k) ----
    for (int s = t; s < NROWS*16; s += NT) {
        int r  = s >> 4;
        int kg = s & 15;
        const float* src = (r < NP)
            ? h1 + ((size_t)b*NP + r)*HH + kg*8
            : h2 + ((size_t)b*NP + (r-NP))*HH + kg*8;
        float4 v0 = *(const float4*)src;
        float4 v1 = *(const float4*)(src + 4);
        unsigned p0 = (unsigned short)bfs(v0.x) | ((unsigned)(unsigned short)bfs(v0.y) << 16);
        unsigned p1 = (unsigned short)bfs(v0.z) | ((unsigned)(unsigned short)bfs(v0.w) << 16);
        unsigned p2 = (unsigned short)bfs(v1.x) | ((unsigned)(unsigned short)bfs(v1.y) << 16);
        unsigned p3 = (unsigned short)bfs(v1.z) | ((unsigned)(unsigned short)bfs(v1.w) << 16);
        *(uint4*)(sAB + r*AROWB + kg*16) = make_uint4(p0,p1,p2,p3);
    }
    if (t < 64) {
        sW2S[t] = W2[hf*64 + (t ^ 1)];    // pair-swapped half for packed numerator
        float c = W2[t] + W2[t + 64];     // CL over the FULL w2
        #pragma unroll
        for (int off = 32; off > 0; off >>= 1) c += __shfl_down(c, off, 64);
        if (t == 0) sCL = (c + b2[0]) * L2E;
    }

    // convert W fragments while staging drains
    bf16x8 wf[4];
    #pragma unroll
    for (int ks = 0; ks < 4; ++ks) {
        short* wp = (short*)&wf[ks];
        #pragma unroll
        for (int j = 0; j < 8; ++j) wp[j] = bfs(wraw[ks][j]);
    }
    __syncthreads();   // B1

    // ---- MFMA: E[m][r][hbl..+4] = exp2(K*P + K*b1) for this h-half ----
    #pragma unroll
    for (int rn = 0; rn < 3; ++rn) {
        int rr   = rn*16 + lr;
        int rowc = (rr < NP) ? rr : NP-1;    // clamp; clamped results discarded
        const char* Ab = sAB + (m*NP + rowc)*AROWB + (l4 << 4);
        f32x4 c = {0.f,0.f,0.f,0.f};
        #pragma unroll
        for (int ks = 0; ks < 4; ++ks) {
            bf16x8 af = *(const bf16x8*)(Ab + ks*64);
            c = __builtin_amdgcn_mfma_f32_16x16x32_bf16(wf[ks], af, c, 0, 0, 0);
        }
        if (rr < NP) {
            float4 ev;
            ev.x = __builtin_amdgcn_exp2f(fmaf(K, c[0], kbK.x));
            ev.y = __builtin_amdgcn_exp2f(fmaf(K, c[1], kbK.y));
            ev.z = __builtin_amdgcn_exp2f(fmaf(K, c[2], kbK.z));
            ev.w = __builtin_amdgcn_exp2f(fmaf(K, c[3], kbK.w));
            *(float4*)(sE + (m*NP + rr)*EST2 + hbl) = ev;
        }
    }
    __syncthreads();   // B2

    // ---- Phase 2 partial: 4x2 pair tiles x 2 h-segs over local 64 h ----
    if (t < 400) {
        const int tile = t >> 1;        // 200 tiles
        const int hs   = t & 1;
        const int it = tile / 20;       // rows it+10rn
        const int jt = tile - it*20;    // cols jt+20cn
        const int h0 = hs << 5;
        const float* e1b = sE + it*EST2 + h0;
        const float* e2b = sE + (NP + jt)*EST2 + h0;
        const float* wpb = sW2S + h0;
        const f32x2 one2 = {1.f, 1.f};
        f32x2 a2[8];
        #pragma unroll
        for (int q = 0; q < 8; ++q) a2[q] = (f32x2){0.f, 0.f};
        #pragma unroll
        for (int s = 0; s < 32; s += 4) {
            f32x4 wv = *(const f32x4*)(wpb + s);
            f32x4 e1v[4], e2v[2];
            #pragma unroll
            for (int rn = 0; rn < 4; ++rn) e1v[rn] = *(const f32x4*)(e1b + rn*10*EST2 + s);
            #pragma unroll
            for (int cn = 0; cn < 2; ++cn) e2v[cn] = *(const f32x4*)(e2b + cn*20*EST2 + s);
            #pragma unroll
            for (int rn = 0; rn < 4; ++rn)
                #pragma unroll
                for (int cn = 0; cn < 2; ++cn) {
                    PB2(a2[rn*2+cn], e1v[rn].lo, e2v[cn].lo, wv.lo);
                    PB2(a2[rn*2+cn], e1v[rn].hi, e2v[cn].hi, wv.hi);
                }
        }
        float a[8];
        #pragma unroll
        for (int q = 0; q < 8; ++q) a[q] = a2[q].x + a2[q].y;
        #pragma unroll
        for (int q = 0; q < 8; ++q) a[q] += __shfl_xor(a[q], 1);   // combine 2 h-segs
        if (hs == 0) {
            #pragma unroll
            for (int rn = 0; rn < 4; ++rn)
                #pragma unroll
                for (int cn = 0; cn < 2; ++cn)
                    sPar[(it + 10*rn)*40 + jt + 20*cn] = a[rn*2+cn];
        }
    }
    __syncthreads();   // B3

    // partials -> ws[bid][1600] (coalesced)
    if (t < 400)
        ((float4*)(ws + (size_t)bid*1600))[t] = ((const float4*)sPar)[t];

    // ---- ticket: second finisher per pair does the combine ----
    __syncthreads();   // B4: all ws stores drained (barrier implies vmcnt(0))
    if (t == 0) {
        __threadfence();                       // release: device-visible
        sTicket = atomicAdd(&cnt[b], 1u);
    }
    __syncthreads();   // B5
    if (sTicket == 0) return;                  // first finisher exits
    __threadfence();                           // acquire before reading partner

    // ---- Phase 3 (last block only): combine halves, softmax, all 80 outputs ----
    const float CL = sCL;
    const float* pw = ws + (size_t)(bid ^ 1) * 1600;   // partner half
    float lsum = 0.f;
    if (t < 400) {
        float4 va = ((const float4*)sPar)[t];          // own half (LDS)
        float4 vb = ((const float4*)pw)[t];
        float4 pu;
        pu.x = __builtin_amdgcn_exp2f(fmaf(va.x + vb.x, -K, CL));
        pu.y = __builtin_amdgcn_exp2f(fmaf(va.y + vb.y, -K, CL));
        pu.z = __builtin_amdgcn_exp2f(fmaf(va.z + vb.z, -K, CL));
        pu.w = __builtin_amdgcn_exp2f(fmaf(va.w + vb.w, -K, CL));
        ((float4*)sPar)[t] = pu;
        lsum = pu.x + pu.y + pu.z + pu.w;
    }
    #pragma unroll
    for (int off = 32; off > 0; off >>= 1) lsum += __shfl_down(lsum, off, 64);
    if ((t & 63) == 0) sRed[t >> 6] = lsum;
    __syncthreads();   // B6
    float Z = 0.f;
    #pragma unroll
    for (int wv = 0; wv < 8; ++wv) Z += sRed[wv];
    const float rZ = __builtin_amdgcn_rcpf(Z);

    if (t < 320) {                        // 40 rows x 8 segs of 5
        const int row = t >> 3, seg = t & 7;
        const float* p = sPar + row*40 + seg*5;
        float s = p[0] + p[1] + p[2] + p[3] + p[4];
        s += __shfl_down(s, 4, 8);
        s += __shfl_down(s, 2, 8);
        s += __shfl_down(s, 1, 8);
        if (seg == 0) out[b*NP + row] = s * rZ;
    } else if (t < 480) {                 // 40 cols x 4 segs of 10 rows
        const int q = t - 320;
        const int col = q >> 2, seg = q & 3;
        float s = 0.f;
        #pragma unroll
        for (int k = 0; k < 10; ++k) s += sPar[(seg*10 + k)*40 + col];
        s += __shfl_down(s, 2, 4);
        s += __shfl_down(s, 1, 4);
        if (seg == 0) out[BB*NP + b*NP + col] = s * rZ;
    }
}

extern "C" void kernel_launch(void* const* d_in, const int* in_sizes, int n_in,
                              void* d_out, int out_size, void* d_ws, size_t ws_size,
                              hipStream_t stream) {
    const float* h1 = (const float*)d_in[0];
    const float* h2 = (const float*)d_in[1];
    // d_in[2], d_in[3] are batch1/batch2 (unused: equal-sized sorted segments)
    const float* W1 = (const float*)d_in[4];
    const float* b1 = (const float*)d_in[5];
    const float* W2 = (const float*)d_in[6];
    const float* b2 = (const float*)d_in[7];
    float* out = (float*)d_out;
    float* ws  = (float*)d_ws;                       // partials: 512*1600 floats
    unsigned* cnt = (unsigned*)(ws + (size_t)NBLK*1600);   // 256 counters after partials

    hipMemsetAsync((void*)cnt, 0, BB * sizeof(unsigned), stream);
    hipLaunchKernelGGL(ddi_half, dim3(NBLK), dim3(NT), 0, stream,
                       h1, h2, W1, b1, W2, b2, ws, cnt, out);
}

// Round 13
// 19.339 us; speedup vs baseline: 4.8430x; 4.8430x over previous
//
#include <hip/hip_runtime.h>
#include <hip/hip_bf16.h>

#define BB 256      // drug pairs
#define NP 40       // atoms per graph
#define HH 128      // hidden dim
#define EST2 68     // E row stride (floats) for the 64-col half (+4 pad)
#define NT 512
#define AROWB 272   // bf16-A LDS row stride bytes (256 + 16 pad)
#define NROWS 80    // A1 rows 0-39, A2 rows 40-79
#define NBLK (2*BB)

typedef __attribute__((ext_vector_type(8))) short bf16x8;
typedef __attribute__((ext_vector_type(4))) float f32x4;
typedef __attribute__((ext_vector_type(2))) float f32x2;

static __device__ __forceinline__ short bfs(float f) {
    union { __hip_bfloat16 h; short s; } u;
    u.h = __float2bfloat16(f);          // RTNE
    return u.s;
}

// packed 2-elem tanh-sum step (R10): acc2 += (wswap*D) * rcp(D.x*D.y)
#define PB2(acc2, e1p, e2p, wsp) do {                              \
    f32x2 D_  = __builtin_elementwise_fma((e1p), (e2p), one2);     \
    float r_  = __builtin_amdgcn_rcpf(D_.x * D_.y);                \
    f32x2 rs_ = {r_, r_};                                          \
    acc2 = __builtin_elementwise_fma((wsp) * D_, rs_, acc2);       \
} while (0)

// K1: block = (pair b, h-half hf). E for 64 h-cols; partial tanh-sums -> ws.
__global__ __launch_bounds__(NT, 4) void ddi_k1(
    const float* __restrict__ h1, const float* __restrict__ h2,
    const float* __restrict__ W1, const float* __restrict__ b1,
    const float* __restrict__ W2, float* __restrict__ ws)
{
    const int bid = blockIdx.x;
    const int b   = bid >> 1;
    const int hf  = bid & 1;
    const int t = threadIdx.x;
    const int l = t & 63;
    const int w = t >> 6;            // 8 waves
    const int l4 = l >> 4;
    const int lr = l & 15;

    __shared__ __align__(16) char  sAB[NROWS*AROWB];   // 21760 B bf16 A1|A2
    __shared__ __align__(16) float sE[2*NP*EST2];      // 21760 B E1|E2 (64-col half)
    __shared__ __align__(16) float sPar[1600];         // 6400 B partials
    __shared__ __align__(16) float sW2S[64];           // w2 half, pair-swapped

    const float K = 2.88539008177792681472f;   // 2*log2(e)

    // ---- W1 fragments for this h-half (A-operand = W^T) ----
    const int m   = w >> 2;          // matrix 0/1
    const int hml = w & 3;           // local h-tile 0..3
    const int hbl = hml*16 + l4*4;   // local E col base
    const float* Wb = W1 + (size_t)m*HH*HH + hf*64 + hml*16 + lr;
    float wraw[4][8];
    #pragma unroll
    for (int ks = 0; ks < 4; ++ks)
        #pragma unroll
        for (int j = 0; j < 8; ++j)
            wraw[ks][j] = Wb[(size_t)(ks*32 + (l4<<3) + j) * HH];
    float4 kbK = make_float4(0.f,0.f,0.f,0.f);
    if (m == 0) {
        float4 bv = *(const float4*)(b1 + hf*64 + hbl);
        kbK = make_float4(K*bv.x, K*bv.y, K*bv.z, K*bv.w);
    }

    // ---- stage A as bf16 (80 rows x full 128 k) ----
    for (int s = t; s < NROWS*16; s += NT) {
        int r  = s >> 4;
        int kg = s & 15;
        const float* src = (r < NP)
            ? h1 + ((size_t)b*NP + r)*HH + kg*8
            : h2 + ((size_t)b*NP + (r-NP))*HH + kg*8;
        float4 v0 = *(const float4*)src;
        float4 v1 = *(const float4*)(src + 4);
        unsigned p0 = (unsigned short)bfs(v0.x) | ((unsigned)(unsigned short)bfs(v0.y) << 16);
        unsigned p1 = (unsigned short)bfs(v0.z) | ((unsigned)(unsigned short)bfs(v0.w) << 16);
        unsigned p2 = (unsigned short)bfs(v1.x) | ((unsigned)(unsigned short)bfs(v1.y) << 16);
        unsigned p3 = (unsigned short)bfs(v1.z) | ((unsigned)(unsigned short)bfs(v1.w) << 16);
        *(uint4*)(sAB + r*AROWB + kg*16) = make_uint4(p0,p1,p2,p3);
    }
    if (t < 64) sW2S[t] = W2[hf*64 + (t ^ 1)];   // pair-swapped half

    // convert W fragments while staging drains
    bf16x8 wf[4];
    #pragma unroll
    for (int ks = 0; ks < 4; ++ks) {
        short* wp = (short*)&wf[ks];
        #pragma unroll
        for (int j = 0; j < 8; ++j) wp[j] = bfs(wraw[ks][j]);
    }
    __syncthreads();   // B1

    // ---- MFMA: E[m][r][hbl..+4] = exp2(K*P [+ K*b1]) for this h-half ----
    #pragma unroll
    for (int rn = 0; rn < 3; ++rn) {
        int rr   = rn*16 + lr;
        int rowc = (rr < NP) ? rr : NP-1;    // clamp; clamped results discarded
        const char* Ab = sAB + (m*NP + rowc)*AROWB + (l4 << 4);
        f32x4 c = {0.f,0.f,0.f,0.f};
        #pragma unroll
        for (int ks = 0; ks < 4; ++ks) {
            bf16x8 af = *(const bf16x8*)(Ab + ks*64);
            c = __builtin_amdgcn_mfma_f32_16x16x32_bf16(wf[ks], af, c, 0, 0, 0);
        }
        if (rr < NP) {
            float4 ev;
            ev.x = __builtin_amdgcn_exp2f(fmaf(K, c[0], kbK.x));
            ev.y = __builtin_amdgcn_exp2f(fmaf(K, c[1], kbK.y));
            ev.z = __builtin_amdgcn_exp2f(fmaf(K, c[2], kbK.z));
            ev.w = __builtin_amdgcn_exp2f(fmaf(K, c[3], kbK.w));
            *(float4*)(sE + (m*NP + rr)*EST2 + hbl) = ev;
        }
    }
    __syncthreads();   // B2

    // ---- Phase 2 partial: 4x2 pair tiles x 2 h-segs over local 64 h ----
    if (t < 400) {
        const int tile = t >> 1;        // 200 tiles
        const int hs   = t & 1;
        const int it = tile / 20;       // rows it+10rn
        const int jt = tile - it*20;    // cols jt+20cn
        const int h0 = hs << 5;
        const float* e1b = sE + it*EST2 + h0;
        const float* e2b = sE + (NP + jt)*EST2 + h0;
        const float* wpb = sW2S + h0;
        const f32x2 one2 = {1.f, 1.f};
        f32x2 a2[8];
        #pragma unroll
        for (int q = 0; q < 8; ++q) a2[q] = (f32x2){0.f, 0.f};
        #pragma unroll
        for (int s = 0; s < 32; s += 4) {
            f32x4 wv = *(const f32x4*)(wpb + s);
            f32x4 e1v[4], e2v[2];
            #pragma unroll
            for (int rn = 0; rn < 4; ++rn) e1v[rn] = *(const f32x4*)(e1b + rn*10*EST2 + s);
            #pragma unroll
            for (int cn = 0; cn < 2; ++cn) e2v[cn] = *(const f32x4*)(e2b + cn*20*EST2 + s);
            #pragma unroll
            for (int rn = 0; rn < 4; ++rn)
                #pragma unroll
                for (int cn = 0; cn < 2; ++cn) {
                    PB2(a2[rn*2+cn], e1v[rn].lo, e2v[cn].lo, wv.lo);
                    PB2(a2[rn*2+cn], e1v[rn].hi, e2v[cn].hi, wv.hi);
                }
        }
        float a[8];
        #pragma unroll
        for (int q = 0; q < 8; ++q) a[q] = a2[q].x + a2[q].y;
        #pragma unroll
        for (int q = 0; q < 8; ++q) a[q] += __shfl_xor(a[q], 1);   // combine 2 h-segs
        if (hs == 0) {
            #pragma unroll
            for (int rn = 0; rn < 4; ++rn)
                #pragma unroll
                for (int cn = 0; cn < 2; ++cn)
                    sPar[(it + 10*rn)*40 + jt + 20*cn] = a[rn*2+cn];
        }
    }
    __syncthreads();   // B3

    // partials -> ws[bid][1600] (coalesced; kernel-end drain = visibility)
    if (t < 400)
        ((float4*)(ws + (size_t)bid*1600))[t] = ((const float4*)sPar)[t];
}

// K2: combine halves, softmax, row/col sums (R12's verified finisher logic).
__global__ __launch_bounds__(NT, 4) void ddi_k2(
    const float* __restrict__ ws, const float* __restrict__ W2,
    const float* __restrict__ b2, float* __restrict__ out)
{
    const int b = blockIdx.x;
    const int t = threadIdx.x;

    __shared__ __align__(16) float sPar[1600];
    __shared__ float sRed[8];
    __shared__ float sCL;

    const float L2E = 1.44269504088896340736f;
    const float K   = 2.88539008177792681472f;

    if (t < 64) {   // CL = (b2 + sum(w2)) * log2e
        float c = W2[t] + W2[t + 64];
        #pragma unroll
        for (int off = 32; off > 0; off >>= 1) c += __shfl_down(c, off, 64);
        if (t == 0) sCL = (c + b2[0]) * L2E;
    }
    __syncthreads();

    const float CL = sCL;
    const float* baseA = ws + (size_t)(2*b)*1600;
    const float* baseB = baseA + 1600;
    float lsum = 0.f;
    if (t < 400) {
        float4 va = ((const float4*)baseA)[t];
        float4 vb = ((const float4*)baseB)[t];
        float4 pu;
        pu.x = __builtin_amdgcn_exp2f(fmaf(va.x + vb.x, -K, CL));
        pu.y = __builtin_amdgcn_exp2f(fmaf(va.y + vb.y, -K, CL));
        pu.z = __builtin_amdgcn_exp2f(fmaf(va.z + vb.z, -K, CL));
        pu.w = __builtin_amdgcn_exp2f(fmaf(va.w + vb.w, -K, CL));
        ((float4*)sPar)[t] = pu;
        lsum = pu.x + pu.y + pu.z + pu.w;
    }
    #pragma unroll
    for (int off = 32; off > 0; off >>= 1) lsum += __shfl_down(lsum, off, 64);
    if ((t & 63) == 0) sRed[t >> 6] = lsum;
    __syncthreads();
    float Z = 0.f;
    #pragma unroll
    for (int wv = 0; wv < 8; ++wv) Z += sRed[wv];
    const float rZ = __builtin_amdgcn_rcpf(Z);

    if (t < 320) {                        // 40 rows x 8 segs of 5
        const int row = t >> 3, seg = t & 7;
        const float* p = sPar + row*40 + seg*5;
        float s = p[0] + p[1] + p[2] + p[3] + p[4];
        s += __shfl_down(s, 4, 8);
        s += __shfl_down(s, 2, 8);
        s += __shfl_down(s, 1, 8);
        if (seg == 0) out[b*NP + row] = s * rZ;
    } else if (t < 480) {                 // 40 cols x 4 segs of 10 rows
        const int q = t - 320;
        const int col = q >> 2, seg = q & 3;
        float s = 0.f;
        #pragma unroll
        for (int k = 0; k < 10; ++k) s += sPar[(seg*10 + k)*40 + col];
        s += __shfl_down(s, 2, 4);
        s += __shfl_down(s, 1, 4);
        if (seg == 0) out[BB*NP + b*NP + col] = s * rZ;
    }
}

extern "C" void kernel_launch(void* const* d_in, const int* in_sizes, int n_in,
                              void* d_out, int out_size, void* d_ws, size_t ws_size,
                              hipStream_t stream) {
    const float* h1 = (const float*)d_in[0];
    const float* h2 = (const float*)d_in[1];
    // d_in[2], d_in[3] are batch1/batch2 (unused: equal-sized sorted segments)
    const float* W1 = (const float*)d_in[4];
    const float* b1 = (const float*)d_in[5];
    const float* W2 = (const float*)d_in[6];
    const float* b2 = (const float*)d_in[7];
    float* out = (float*)d_out;
    float* ws  = (float*)d_ws;   // 512*1600*4 = 3.27 MB

    hipLaunchKernelGGL(ddi_k1, dim3(NBLK), dim3(NT), 0, stream,
                       h1, h2, W1, b1, W2, ws);
    hipLaunchKernelGGL(ddi_k2, dim3(BB), dim3(NT), 0, stream,
                       ws, W2, b2, out);
}

// Round 14
// 16.613 us; speedup vs baseline: 5.6376x; 1.1641x over previous
//
#include <hip/hip_runtime.h>
#include <hip/hip_bf16.h>

#define BB 256      // drug pairs
#define NP 40       // atoms per graph
#define HH 128      // hidden dim
#define EST 132     // E row stride (floats); 528B = 33*16
#define SST 44      // sSE row stride
#define NT 1024
#define AROWB 272   // bf16-A LDS row stride in bytes (256 + 16 pad)
#define NROWP 48    // A rows padded to 3 MFMA tiles (rows 40-47 stale, outputs discarded)

typedef __attribute__((ext_vector_type(8))) short bf16x8;
typedef __attribute__((ext_vector_type(4))) float f32x4;
typedef __attribute__((ext_vector_type(2))) float f32x2;

static __device__ __forceinline__ unsigned short f2bf(float f) {
    unsigned u = __float_as_uint(f);                     // RTNE fp32 -> bf16
    return (unsigned short)((u + 0x7FFFu + ((u >> 16) & 1u)) >> 16);
}

// packed 2-elem tanh-sum step: acc2 += (wswap*D) * rcp(D.x*D.y)
#define PB2(acc2, e1p, e2p, wsp) do {                              \
    f32x2 D_  = __builtin_elementwise_fma((e1p), (e2p), one2);     \
    float r_  = __builtin_amdgcn_rcpf(D_.x * D_.y);                \
    f32x2 rs_ = {r_, r_};                                          \
    acc2 = __builtin_elementwise_fma((wsp) * D_, rs_, acc2);       \
} while (0)

__global__ __launch_bounds__(NT, 4) void ddi_fused(
    const float* __restrict__ h1, const float* __restrict__ h2,
    const float* __restrict__ W1, const float* __restrict__ b1,
    const float* __restrict__ W2, const float* __restrict__ b2,
    float* __restrict__ out)
{
    const int b = blockIdx.x;
    const int t = threadIdx.x;
    const int l = t & 63;
    const int w = t >> 6;

    __shared__ __align__(16) char  sAB[2*NROWP*AROWB];   // 26112 B bf16 A1,A2
    __shared__ __align__(16) float sE[2*NP*EST];         // 42240 B E1,E2
    __shared__ __align__(16) float sSE[NP*SST];          // 7040 B
    __shared__ __align__(16) float sW2S[HH];             // w2 pair-swapped
    __shared__ float sRed[NT/64];
    __shared__ float sCL;

    const float L2E = 1.44269504088896340736f;
    const float K   = 2.88539008177792681472f;   // 2*log2(e)

    // ---- A-tile loads FIRST: they gate B1. Coalesced float4. ----
    // pass 1: item t (0..1023); pass 2: item t+1024 (t<256 only)
    const int ms1  = (t >= NP*16) ? 1 : 0;
    const int rem1 = t - ms1*NP*16;
    const int r1 = rem1 >> 4, kg1 = rem1 & 15;
    const float* src1 = (ms1 ? h2 : h1) + ((size_t)b*NP + r1)*HH + kg1*8;
    float4 a1v0 = *(const float4*)src1;
    float4 a1v1 = *(const float4*)(src1 + 4);
    const bool has2 = (t < 2*NP*16 - NT);          // t < 256 -> A2 rows 24..39
    const int r2 = 24 + (t >> 4), kg2 = t & 15;
    float4 a2v0 = make_float4(0,0,0,0), a2v1 = a2v0;
    if (has2) {
        const float* src2 = h2 + ((size_t)b*NP + r2)*HH + kg2*8;
        a2v0 = *(const float4*)src2;
        a2v1 = *(const float4*)(src2 + 4);
    }

    // ---- W1 fragments + b1 + W2 issued AFTER A (consumed after B1/B2) ----
    const int m  = w >> 3;
    const int hm = w & 7;
    const int hbase = hm*16 + ((l >> 4) << 2);
    const float* Wb = W1 + (size_t)m*HH*HH + hm*16 + (l & 15);
    float wraw[4][8];
    #pragma unroll
    for (int ks = 0; ks < 4; ++ks)
        #pragma unroll
        for (int j = 0; j < 8; ++j)
            wraw[ks][j] = Wb[(size_t)(ks*32 + ((l>>4)<<3) + j) * HH];
    float4 kbK = make_float4(0.f,0.f,0.f,0.f);
    if (m == 0) {
        float4 bv = *(const float4*)(b1 + hbase);
        kbK = make_float4(K*bv.x, K*bv.y, K*bv.z, K*bv.w);
    }
    float w2s = 0.f, w2a = 0.f, w2b = 0.f;
    if (t < HH) w2s = W2[t ^ 1];                 // for sW2S (stored after B1)
    if (t < 64) { w2a = W2[t]; w2b = W2[t + 64]; }   // for CL

    // ---- cvt + store A to LDS (waits only the A loads via counted vmcnt) ----
    {
        unsigned p0 = f2bf(a1v0.x) | ((unsigned)f2bf(a1v0.y) << 16);
        unsigned p1 = f2bf(a1v0.z) | ((unsigned)f2bf(a1v0.w) << 16);
        unsigned p2 = f2bf(a1v1.x) | ((unsigned)f2bf(a1v1.y) << 16);
        unsigned p3 = f2bf(a1v1.z) | ((unsigned)f2bf(a1v1.w) << 16);
        *(uint4*)(sAB + (ms1*NROWP + r1)*AROWB + kg1*16) = make_uint4(p0,p1,p2,p3);
    }
    if (has2) {
        unsigned p0 = f2bf(a2v0.x) | ((unsigned)f2bf(a2v0.y) << 16);
        unsigned p1 = f2bf(a2v0.z) | ((unsigned)f2bf(a2v0.w) << 16);
        unsigned p2 = f2bf(a2v1.x) | ((unsigned)f2bf(a2v1.y) << 16);
        unsigned p3 = f2bf(a2v1.z) | ((unsigned)f2bf(a2v1.w) << 16);
        *(uint4*)(sAB + (NROWP + r2)*AROWB + kg2*16) = make_uint4(p0,p1,p2,p3);
    }
    __syncthreads();   // B1 — gated only on A staging

    // ---- post-B1: convert W, stage sW2S/sCL (consumed after B2) ----
    bf16x8 wf[4];
    #pragma unroll
    for (int ks = 0; ks < 4; ++ks) {
        unsigned short* wp = (unsigned short*)&wf[ks];
        #pragma unroll
        for (int j = 0; j < 8; ++j) wp[j] = f2bf(wraw[ks][j]);
    }
    if (t < HH) sW2S[t] = w2s;
    if (t < 64) {
        float c = w2a + w2b;
        #pragma unroll
        for (int off = 32; off > 0; off >>= 1) c += __shfl_down(c, off, 64);
        if (t == 0) sCL = (c + b2[0]) * L2E;
    }

    // ---- MFMA: P^T(16h x 16r) = W^T * A^T; E = exp2(K*P + K*b1), rows<40 ----
    {
        const char* Ab = sAB + (m*NROWP + (l & 15))*AROWB + ((l >> 4) << 4);
        #pragma unroll
        for (int rn = 0; rn < 3; ++rn) {
            f32x4 c = {0.f, 0.f, 0.f, 0.f};
            #pragma unroll
            for (int ks = 0; ks < 4; ++ks) {
                bf16x8 af = *(const bf16x8*)(Ab + rn*(16*AROWB) + ks*64);
                c = __builtin_amdgcn_mfma_f32_16x16x32_bf16(wf[ks], af, c, 0, 0, 0);
            }
            int r = rn*16 + (l & 15);
            if (r < NP) {
                float4 ev;
                ev.x = __builtin_amdgcn_exp2f(fmaf(K, c[0], kbK.x));
                ev.y = __builtin_amdgcn_exp2f(fmaf(K, c[1], kbK.y));
                ev.z = __builtin_amdgcn_exp2f(fmaf(K, c[2], kbK.z));
                ev.w = __builtin_amdgcn_exp2f(fmaf(K, c[3], kbK.w));
                *(float4*)(sE + (m*NP + r)*EST + hbase) = ev;
            }
        }
    }
    __syncthreads();   // B2 — sE, sW2S, sCL all visible

    // ---- Phase 2: 4x2 pair tiles x 4-way h-split, packed fp32 (R10 exact) ----
    float lsum = 0.f;
    if (t < 800) {
        const int tile = t >> 2;
        const int hseg = t & 3;
        const int it = tile / 20;
        const int jt = tile - it * 20;
        const int h0 = hseg << 5;
        const float* e1b = sE + it*EST + h0;               // + rn*10*EST
        const float* e2b = sE + (NP + jt)*EST + h0;        // + cn*20*EST
        const float* wpb = sW2S + h0;
        const f32x2 one2 = {1.f, 1.f};
        f32x2 a2[8];
        #pragma unroll
        for (int q = 0; q < 8; ++q) a2[q] = (f32x2){0.f, 0.f};
        #pragma unroll
        for (int s = 0; s < 32; s += 4) {
            f32x4 wv = *(const f32x4*)(wpb + s);
            f32x4 e1v[4], e2v[2];
            #pragma unroll
            for (int rn = 0; rn < 4; ++rn) e1v[rn] = *(const f32x4*)(e1b + rn*10*EST + s);
            #pragma unroll
            for (int cn = 0; cn < 2; ++cn) e2v[cn] = *(const f32x4*)(e2b + cn*20*EST + s);
            #pragma unroll
            for (int rn = 0; rn < 4; ++rn)
                #pragma unroll
                for (int cn = 0; cn < 2; ++cn) {
                    PB2(a2[rn*2+cn], e1v[rn].lo, e2v[cn].lo, wv.lo);
                    PB2(a2[rn*2+cn], e1v[rn].hi, e2v[cn].hi, wv.hi);
                }
        }
        float a[8];
        #pragma unroll
        for (int q = 0; q < 8; ++q) a[q] = a2[q].x + a2[q].y;
        #pragma unroll
        for (int q = 0; q < 8; ++q) {
            a[q] += __shfl_xor(a[q], 1);
            a[q] += __shfl_xor(a[q], 2);
        }
        float s0 = (hseg==0) ? a[0] : (hseg==1) ? a[2] : (hseg==2) ? a[4] : a[6];
        float s1 = (hseg==0) ? a[1] : (hseg==1) ? a[3] : (hseg==2) ? a[5] : a[7];
        const float CL = sCL;
        const int row = it + 10*hseg;
        float pu0 = __builtin_amdgcn_exp2f(fmaf(s0, -K, CL));
        float pu1 = __builtin_amdgcn_exp2f(fmaf(s1, -K, CL));
        sSE[row*SST + jt]      = pu0;
        sSE[row*SST + jt + 20] = pu1;
        lsum = pu0 + pu1;
    }

    // ---- Z reduction ----
    #pragma unroll
    for (int off = 32; off > 0; off >>= 1) lsum += __shfl_down(lsum, off, 64);
    if ((t & 63) == 0) sRed[t >> 6] = lsum;
    __syncthreads();   // B3
    float Z = 0.f;
    #pragma unroll
    for (int wv = 0; wv < NT/64; ++wv) Z += sRed[wv];
    const float rZ = __builtin_amdgcn_rcpf(Z);

    // ---- Phase 3: parallel row/col sums ----
    if (t < 320) {
        const int row = t >> 3, seg = t & 7;
        const float* p = sSE + row*SST + seg*5;
        float s = p[0] + p[1] + p[2] + p[3] + p[4];
        s += __shfl_down(s, 4, 8);
        s += __shfl_down(s, 2, 8);
        s += __shfl_down(s, 1, 8);
        if (seg == 0) out[b*NP + row] = s * rZ;
    } else if (t < 640) {
        const int q = t - 320;
        const int col = q >> 3, seg = q & 7;
        float s = 0.f;
        #pragma unroll
        for (int k = 0; k < 5; ++k) s += sSE[(seg*5 + k)*SST + col];
        s += __shfl_down(s, 4, 8);
        s += __shfl_down(s, 2, 8);
        s += __shfl_down(s, 1, 8);
        if (seg == 0) out[BB*NP + b*NP + col] = s * rZ;
    }
}

extern "C" void kernel_launch(void* const* d_in, const int* in_sizes, int n_in,
                              void* d_out, int out_size, void* d_ws, size_t ws_size,
                              hipStream_t stream) {
    const float* h1 = (const float*)d_in[0];
    const float* h2 = (const float*)d_in[1];
    // d_in[2], d_in[3] are batch1/batch2 (unused: equal-sized sorted segments)
    const float* W1 = (const float*)d_in[4];
    const float* b1 = (const float*)d_in[5];
    const float* W2 = (const float*)d_in[6];
    const float* b2 = (const float*)d_in[7];
    float* out = (float*)d_out;

    hipLaunchKernelGGL(ddi_fused, dim3(BB), dim3(NT), 0, stream,
                       h1, h2, W1, b1, W2, b2, out);
}